// Round 11
// baseline (110.654 us; speedup 1.0000x reference)
//
#include <hip/hip_runtime.h>
#include <hip/hip_bf16.h>
#include <utility>

#define D_DIM 256
#define WID   33
#define CEN   16
#define RSTR  32                 // output rows per block (M = 2 tiles of 16)
#define KDIM  64                 // window rows (K = 2 steps of 32)
#define BPAD  72                 // banded-LDS row stride (dwords): 16B-aligned

// R10 post-mortem: broadcast ds_reads of weights = ~300 LDS-pipe instrs/wave
// ~= 90us chip-wide -> LDS issue-bound. This is a banded matmul:
// Out[32,256] = Wband[32,64] @ X[64,256] per strip. MFMA shares weights
// across lanes in HW; weights -> A-frags (once), x -> B-frags (once),
// 16 mfma per wave. Layout note: any slot->k bijection is correct as long
// as A and B use the SAME one (MFMA contracts slot-wise); m/n = lane&15
// per the verified C/D mapping (col=lane&15, row=(lane>>4)*4+reg).

typedef __bf16 bf16x8 __attribute__((ext_vector_type(8)));
typedef float  f32x4  __attribute__((ext_vector_type(4)));

template <int MT, int KS, size_t... Js>
__device__ __forceinline__ bf16x8 afrag(const float (&lw)[RSTR * BPAD], int lane,
                                        std::index_sequence<Js...>) {
    const int base = (MT * 16 + (lane & 15)) * BPAD + KS * 32 + 8 * (lane >> 4);
    bf16x8 v;
    ((v[(int)Js] = (__bf16)lw[base + (int)Js]), ...);
    return v;
}

template <int KS, int NT, size_t... Js>
__device__ __forceinline__ bf16x8 bfrag(const float* __restrict__ xw, int p0, int N,
                                        bool interior, std::index_sequence<Js...>) {
    bf16x8 v;
    ((v[(int)Js] = (__bf16)((interior ||
                             (unsigned)(p0 + KS * 32 + (int)Js) < (unsigned)N)
                                ? xw[(ptrdiff_t)(KS * 32 + (int)Js) * D_DIM + NT * 16]
                                : 0.0f)),
     ...);
    return v;
}

template <int KS, size_t... NTs>
__device__ __forceinline__ void do_ks(f32x4 (&acc)[8], const float (&lw)[RSTR * BPAD],
                                      int lane, const float* __restrict__ xw, int p0,
                                      int N, bool interior,
                                      std::index_sequence<NTs...>) {
    const bf16x8 a0 = afrag<0, KS>(lw, lane, std::make_index_sequence<8>{});
    const bf16x8 a1 = afrag<1, KS>(lw, lane, std::make_index_sequence<8>{});
    (([&] {
         const bf16x8 bv = bfrag<KS, (int)NTs>(xw, p0, N, interior,
                                               std::make_index_sequence<8>{});
         acc[(int)NTs] = __builtin_amdgcn_mfma_f32_16x16x32_bf16(
             a0, bv, acc[(int)NTs], 0, 0, 0);
         acc[4 + (int)NTs] = __builtin_amdgcn_mfma_f32_16x16x32_bf16(
             a1, bv, acc[4 + (int)NTs], 0, 0, 0);
     }()),
     ...);
}

template <size_t... Rs>
__device__ __forceinline__ void calc_inv(float (&inv)[8], const float (&lsz)[RSTR],
                                         int row4, std::index_sequence<Rs...>) {
    ((inv[(int)Rs] = __builtin_amdgcn_rcpf(
          fmaxf(lsz[((int)Rs / 4) * 16 + row4 + ((int)Rs % 4)], 1e-6f))),
     ...);
}

template <size_t... Ts>
__device__ __forceinline__ void store_all(const f32x4 (&acc)[8], const float (&inv)[8],
                                          float* __restrict__ ob, int row4,
                                          std::index_sequence<Ts...>) {
    (([&] {
         constexpr int t = (int)Ts / 4, r = (int)Ts % 4;
         constexpr int mt = t / 4, nt = t % 4;
         ob[(size_t)((mt * 16 + r) * D_DIM + nt * 16) + (size_t)row4 * D_DIM] =
             acc[t][r] * inv[mt * 4 + r];
     }()),
     ...);
}

__global__ __launch_bounds__(256, 4) void local_enc_mfma(
    const float* __restrict__ x, const float* __restrict__ sizev,
    const float* __restrict__ sm, float* __restrict__ out, int N) {
    __shared__ __align__(16) float lw[RSTR * BPAD];   // banded weights, zero-padded
    __shared__ float lsz[RSTR];

    const int tid  = threadIdx.x;
    const int lane = tid & 63;
    const int wv   = tid >> 6;          // wave 0..3 -> d-slice of 64
    const int b    = blockIdx.y;
    const int n0   = blockIdx.x * RSTR;

    const size_t bN = (size_t)b * N;
    const float* __restrict__ smb = sm + bN * WID;

    // stage banded weights: lw[r][k] = sm[n0+r][k-r] if 0<=k-r<33 && k<64 else 0
    for (int s = tid; s < RSTR * BPAD; s += D_DIM) {
        const int r   = s / BPAD;
        const int k   = s - r * BPAD;
        const int off = k - r;
        lw[s] = (k < KDIM && off >= 0 && off < WID)
                    ? smb[(size_t)(n0 + r) * WID + off]
                    : 0.0f;
    }
    if (tid < RSTR) lsz[tid] = sizev[bN + n0 + tid];
    __syncthreads();

    // B-operand: X[k][d], k=0..63 -> x position p = n0-16+k (0 if OOB)
    const int p0    = n0 - CEN + 8 * (lane >> 4);    // this lane's k-slot base
    const int wbase = wv * 64;
    const float* __restrict__ xw =
        x + ((ptrdiff_t)bN + p0) * D_DIM + wbase + (lane & 15);
    const bool interior = (n0 >= CEN) && (n0 - CEN + KDIM <= N);

    f32x4 acc[8] = {};
    do_ks<0>(acc, lw, lane, xw, p0, N, interior, std::make_index_sequence<4>{});
    do_ks<1>(acc, lw, lane, xw, p0, N, interior, std::make_index_sequence<4>{});

    const int row4 = 4 * (lane >> 4);
    float inv[8];
    calc_inv(inv, lsz, row4, std::make_index_sequence<8>{});

    float* __restrict__ ob = out + (bN + n0) * D_DIM + wbase + (lane & 15);
    store_all(acc, inv, ob, row4, std::make_index_sequence<32>{});
}

extern "C" void kernel_launch(void* const* d_in, const int* in_sizes, int n_in,
                              void* d_out, int out_size, void* d_ws, size_t ws_size,
                              hipStream_t stream) {
    const float* x  = (const float*)d_in[0];
    const float* sz = (const float*)d_in[1];
    const float* sm = (const float*)d_in[2];
    float* out = (float*)d_out;

    const int B = 8;
    const int N = 16384;

    dim3 grid(N / RSTR, B, 1);   // 512 x 8 = 4096 blocks
    dim3 block(D_DIM, 1, 1);
    local_enc_mfma<<<grid, block, 0, stream>>>(x, sz, sm, out, N);
}